// Round 3
// baseline (191.344 us; speedup 1.0000x reference)
//
#include <hip/hip_runtime.h>

#define H 65536
#define CIN 64
#define COUT 128
#define NK 27
#define KTOT (NK*CIN)   // 1728
#define NBLK 128        // points per block (4 waves, 2x2: 64o x 64n each)

typedef unsigned short u16;
typedef unsigned int   u32;
typedef __attribute__((ext_vector_type(8))) short short8;   // 8 bf16 (MFMA frag)
typedef __attribute__((ext_vector_type(4))) float f32x4;    // MFMA acc
typedef __attribute__((ext_vector_type(4))) unsigned int u32x4;

__device__ __forceinline__ u16 f2bf(float f) {
    u32 u = __float_as_uint(f);
    u = (u + 0x7FFFu + ((u >> 16) & 1u)) >> 16;   // RNE
    return (u16)u;
}

// ---------------------------------------------------------------------------
// Kernel 1a: x (64 x 65536 f32, c-major) -> x_t (65536 x 64 bf16, point-major)
__global__ __launch_bounds__(256) void transpose_x(const float* __restrict__ x,
                                                   u16* __restrict__ xt) {
    const int h = blockIdx.x * 256 + threadIdx.x;
    u32 pk[32];
#pragma unroll
    for (int cp = 0; cp < 32; ++cp) {
        float f0 = x[(2 * cp)     * H + h];
        float f1 = x[(2 * cp + 1) * H + h];
        pk[cp] = (u32)f2bf(f0) | ((u32)f2bf(f1) << 16);
    }
    u32x4* dst = (u32x4*)(xt + (size_t)h * CIN);
#pragma unroll
    for (int i = 0; i < 8; ++i)
        dst[i] = *(u32x4*)&pk[i * 4];
}

// ---------------------------------------------------------------------------
// Kernel 1b: w (128 x 64 x 27 f32) -> wbF, MFMA-fragment-ordered:
// wbF[((fb*27 + k)*2 + hh)*512 + lane*8 + j] = bf16(w[fb*16+(lane&15)][hh*32+(lane>>4)*8+j][k])
// so an A-fragment load is one fully-coalesced 1KB wave read. Also zeroes BN sums.
__global__ __launch_bounds__(256) void conv_w(const float* __restrict__ w,
                                              u16* __restrict__ wbF,
                                              float* __restrict__ sums) {
    const int tid = blockIdx.x * 256 + threadIdx.x;
    if (blockIdx.x == 0) sums[threadIdx.x] = 0.f;   // sum[128], sumsq[128]
    if (tid < COUT * KTOT) {
        const int jj   = tid & 7;
        const int lane = (tid >> 3) & 63;
        const int hh   = (tid >> 9) & 1;
        const int t2   = tid >> 10;        // fb*27 + k, t2 in [0,216)
        const int k    = t2 % 27;
        const int fb   = t2 / 27;
        const int o    = fb * 16 + (lane & 15);
        const int c    = hh * 32 + (lane >> 4) * 8 + jj;
        wbF[tid] = f2bf(w[(o * CIN + c) * NK + k]);
    }
}

// ---------------------------------------------------------------------------
// Kernel 2: fused gather + GEMM + BN partial sums. NO LDS data path, NO k-loop
// barriers: B fragments gathered directly from xt per lane; double-buffered regs.
__global__ __launch_bounds__(256, 2) void conv_mfma(const u16* __restrict__ xt,
                                                    const u16* __restrict__ wbF,
                                                    const int* __restrict__ neigh,
                                                    float* __restrict__ out,
                                                    float* __restrict__ sums) {
    __shared__ int sIdx[NBLK * NK];   // 13824 B

    const int tid  = threadIdx.x;
    const int lane = tid & 63;
    const int w    = tid >> 6;        // wave 0..3
    const int wo   = w >> 1;          // o-half (64 each)
    const int wn   = w & 1;           // n-half (64 each)
    const int n0   = blockIdx.x * NBLK;

    for (int i = tid; i < NBLK * NK; i += 256)
        sIdx[i] = neigh[n0 * NK + i];
    __syncthreads();                   // only barrier in the kernel

    const int r16 = lane & 15;
    const int q   = lane >> 4;

    f32x4 acc[4][4] = {};              // [o-frag][n-frag]

    // A base: fragment chunk per (fb,k,hh) is 512 u16; fb = wo*4 + f
    const u16* aBase = wbF + (size_t)(wo * 4 * NK) * 1024 + lane * 8;
    // B gather: lane reads 16B at xt[idx*64 + hh*32 + q*8]

    int    idA[4], idB[4];
    short8 A0[8], A1[8], B0[8], B1[8];

#define LOADIDX(K, ID)                                                   \
    { _Pragma("unroll") for (int nf = 0; nf < 4; ++nf)                   \
        ID[nf] = sIdx[(wn * 64 + nf * 16 + r16) * NK + (K)]; }
#define LOADB(ID, B)                                                     \
    { _Pragma("unroll") for (int nf = 0; nf < 4; ++nf) {                 \
        const u16* p = xt + (size_t)(u32)ID[nf] * 64 + q * 8;            \
        B[nf * 2]     = *(const short8*)(p);                             \
        B[nf * 2 + 1] = *(const short8*)(p + 32); } }
#define LOADA(K, A)                                                      \
    { _Pragma("unroll") for (int f = 0; f < 4; ++f) {                    \
        const u16* p = aBase + (size_t)(f * NK + (K)) * 1024;            \
        A[f * 2]     = *(const short8*)(p);                              \
        A[f * 2 + 1] = *(const short8*)(p + 512); } }
#define MFMAK(A, B)                                                      \
    { _Pragma("unroll") for (int hh = 0; hh < 2; ++hh)                   \
      _Pragma("unroll") for (int f = 0; f < 4; ++f)                      \
      _Pragma("unroll") for (int nf = 0; nf < 4; ++nf)                   \
        acc[f][nf] = __builtin_amdgcn_mfma_f32_16x16x32_bf16(            \
            A[f * 2 + hh], B[nf * 2 + hh], acc[f][nf], 0, 0, 0); }

    LOADIDX(0, idA) LOADB(idA, B0) LOADA(0, A0)

    for (int k = 0; k < NK - 1; k += 2) {     // k = 0,2,...,24
        LOADIDX(k + 1, idB) LOADB(idB, B1) LOADA(k + 1, A1)
        MFMAK(A0, B0)
        LOADIDX(k + 2, idA) LOADB(idA, B0) LOADA(k + 2, A0)
        MFMAK(A1, B1)
    }
    MFMAK(A0, B0)                              // k = 26

#undef LOADIDX
#undef LOADB
#undef LOADA
#undef MFMAK

    // epilogue: C/D layout: col(n) = lane&15, row(o) = q*4 + r
#pragma unroll
    for (int f = 0; f < 4; ++f)
#pragma unroll
        for (int nf = 0; nf < 4; ++nf)
#pragma unroll
            for (int r = 0; r < 4; ++r) {
                const int o = wo * 64 + f * 16 + q * 4 + r;
                const int n = n0 + wn * 64 + nf * 16 + r16;
                out[(size_t)o * H + n] = acc[f][nf][r];
            }

    // fused BN partial sums: reduce over this wave's 64 n per o, then atomicAdd
#pragma unroll
    for (int f = 0; f < 4; ++f)
#pragma unroll
        for (int r = 0; r < 4; ++r) {
            float sv = acc[f][0][r] + acc[f][1][r] + acc[f][2][r] + acc[f][3][r];
            float sq = acc[f][0][r] * acc[f][0][r] + acc[f][1][r] * acc[f][1][r]
                     + acc[f][2][r] * acc[f][2][r] + acc[f][3][r] * acc[f][3][r];
#pragma unroll
            for (int m = 1; m < 16; m <<= 1) {
                sv += __shfl_xor(sv, m, 64);
                sq += __shfl_xor(sq, m, 64);
            }
            if (r16 == 0) {
                const int o = wo * 64 + f * 16 + q * 4 + r;
                atomicAdd(&sums[o], sv);
                atomicAdd(&sums[COUT + o], sq);
            }
        }
}

// ---------------------------------------------------------------------------
// Kernel 3: BN + ReLU with inline stats (sums accumulated by conv), float4.
__global__ __launch_bounds__(256) void bn_relu(float* __restrict__ out,
                                               const float* __restrict__ sums,
                                               const float* __restrict__ gamma,
                                               const float* __restrict__ beta) {
    const int idx = blockIdx.x * 256 + threadIdx.x;  // float4 index
    const int o = idx >> 14;                          // 16384 float4 per channel
    const float mean = sums[o] * (1.f / (float)H);
    const float var  = sums[COUT + o] * (1.f / (float)H) - mean * mean;
    const float a = gamma[o] * rsqrtf(var + 1e-5f);
    const float b = beta[o] - mean * a;
    float4* p = (float4*)out;
    float4 v = p[idx];
    v.x = fmaxf(fmaf(v.x, a, b), 0.f);
    v.y = fmaxf(fmaf(v.y, a, b), 0.f);
    v.z = fmaxf(fmaf(v.z, a, b), 0.f);
    v.w = fmaxf(fmaf(v.w, a, b), 0.f);
    p[idx] = v;
}

// ---------------------------------------------------------------------------
extern "C" void kernel_launch(void* const* d_in, const int* in_sizes, int n_in,
                              void* d_out, int out_size, void* d_ws, size_t ws_size,
                              hipStream_t stream) {
    const float* x     = (const float*)d_in[0];  // (1,64,65536,1)
    const int*   neigh = (const int*)d_in[1];    // (65536,27)
    const float* w     = (const float*)d_in[2];  // (128,64,27)
    const float* gamma = (const float*)d_in[3];
    const float* beta  = (const float*)d_in[4];
    float* out = (float*)d_out;                  // (1,128,65536,1)

    char* ws = (char*)d_ws;
    u16* xt  = (u16*)ws;                              // 8388608 B
    u16* wbF = (u16*)(ws + 8388608);                  // 442368 B
    float* sums = (float*)(ws + 8388608 + 442368);    // 256 floats

    transpose_x<<<H / 256, 256, 0, stream>>>(x, xt);
    conv_w<<<(COUT * KTOT + 255) / 256, 256, 0, stream>>>(w, wbF, sums);
    conv_mfma<<<H / NBLK, 256, 0, stream>>>(xt, wbF, neigh, out, sums);
    bn_relu<<<(COUT * H / 4) / 256, 256, 0, stream>>>(out, sums, gamma, beta);
}